// Round 7
// baseline (1820.851 us; speedup 1.0000x reference)
//
#include <hip/hip_runtime.h>
#include <hip/hip_cooperative_groups.h>

namespace cg = cooperative_groups;

#define NN 2048
#define DDIM 128
#define NHEAD 4
#define DH 32
#define NL 6

typedef __attribute__((ext_vector_type(8))) __bf16 bf16x8;
typedef __attribute__((ext_vector_type(4))) float f32x4;

__device__ __forceinline__ unsigned int f2bf(float x) {
  unsigned int u = __float_as_uint(x);
  u += 0x7fff + ((u >> 16) & 1);   // RNE
  return u >> 16;
}
__device__ __forceinline__ unsigned int pk2(float a, float b) {
  return f2bf(a) | (f2bf(b) << 16);
}
__device__ __forceinline__ float bf2f(unsigned short u) {
  return __uint_as_float(((unsigned int)u) << 16);
}

// ---------------------------------------------------------------------------
// Weight cast fp32->bf16 (unchanged from R6).
// ---------------------------------------------------------------------------
__global__ __launch_bounds__(256) void wcast_kernel(
    const float* __restrict__ Wq, const float* __restrict__ Wk,
    const float* __restrict__ Wv, const float* __restrict__ W1,
    const float* __restrict__ W2,
    unsigned short* __restrict__ Wqkv, unsigned short* __restrict__ Wb2,
    unsigned short* __restrict__ Wmix) {
  int idx = (blockIdx.x * 256 + threadIdx.x) * 4;
  if (idx >= 688128) return;
  const float* src; unsigned short* dst; int soff, doff;
  if (idx < 98304)       { src = Wq; soff = idx; dst = Wqkv; doff = idx; }
  else if (idx < 196608) { src = Wk; soff = idx - 98304; dst = Wqkv; doff = idx; }
  else if (idx < 294912) { src = Wv; soff = idx - 196608; dst = Wqkv; doff = idx; }
  else if (idx < 491520) { src = W2; soff = idx - 294912; dst = Wb2; doff = soff; }
  else {
    int f = idx - 491520;
    int l = f >> 15, rem = f & 32767;
    int i = rem >> 7, c = rem & 127;
    src = W1; soff = (l << 16) + (i << 8) + c;
    dst = Wmix; doff = (l << 16) + (i << 8) + c;
  }
  float4 v = *(const float4*)&src[soff];
  uint2 p = { pk2(v.x, v.y), pk2(v.z, v.w) };
  *(uint2*)&dst[doff] = p;
}

// ---------------------------------------------------------------------------
// Wfuse + b1 fold (unchanged from R6).
// ---------------------------------------------------------------------------
__global__ __launch_bounds__(256) void wfuse_kernel(
    const float* __restrict__ W1, const float* __restrict__ Wm,
    unsigned short* __restrict__ Wmix,
    const float* __restrict__ bmv, const float* __restrict__ b1,
    float* __restrict__ b1m) {
  const int l = blockIdx.z;
  const int bj = blockIdx.x * 64;
  const int bi = blockIdx.y * 64;
  __shared__ float Ws[32][65];
  __shared__ float Xs[32][64];
  const int t = threadIdx.x;
  const int ti = (t >> 4) << 2;
  const int tj = (t & 15) << 2;
  float acc[4][4] = {{0.f}};
  for (int k0 = 0; k0 < 128; k0 += 32) {
#pragma unroll
    for (int i = 0; i < 8; ++i) {
      int e = t + i * 256;
      int ii = e >> 5, kk = e & 31;
      Ws[kk][ii] = W1[(size_t)(l << 16) + (bi + ii) * 256 + 128 + k0 + kk];
    }
#pragma unroll
    for (int i = 0; i < 2; ++i) {
      int e = t + i * 256;
      int r = e >> 4, c4 = e & 15;
      *(float4*)&Xs[r][c4 * 4] = *(const float4*)&Wm[(size_t)l * 16384 + (k0 + r) * 128 + bj + c4 * 4];
    }
    __syncthreads();
#pragma unroll
    for (int kk = 0; kk < 32; ++kk) {
      float a[4];
      a[0] = Ws[kk][ti]; a[1] = Ws[kk][ti + 1]; a[2] = Ws[kk][ti + 2]; a[3] = Ws[kk][ti + 3];
      float4 b4 = *(const float4*)&Xs[kk][tj];
      float bb[4] = {b4.x, b4.y, b4.z, b4.w};
#pragma unroll
      for (int i = 0; i < 4; ++i)
#pragma unroll
        for (int j = 0; j < 4; ++j) acc[i][j] += a[i] * bb[j];
    }
    __syncthreads();
  }
#pragma unroll
  for (int i = 0; i < 4; ++i) {
    uint2 p = { pk2(acc[i][0], acc[i][1]), pk2(acc[i][2], acc[i][3]) };
    *(uint2*)&Wmix[(size_t)(l << 16) + (bi + ti + i) * 256 + 128 + bj + tj] = p;
  }
  if (blockIdx.x == 0 && blockIdx.y == 0) {
    float a = b1[l * 256 + t];
    const float* wr = &W1[(size_t)(l << 16) + t * 256 + 128];
    const float* bp = &bmv[l * 128];
    for (int k = 0; k < 128; k += 4)
      a += wr[k] * bp[k] + wr[k + 1] * bp[k + 1] + wr[k + 2] * bp[k + 2] + wr[k + 3] * bp[k + 3];
    b1m[l * 256 + t] = a;
  }
}

// ---------------------------------------------------------------------------
// desc fp32 [c][n] -> desc_T bf16 [n][128] + fp32 residual copy (unchanged).
// ---------------------------------------------------------------------------
__global__ __launch_bounds__(256) void desc_cast_kernel(
    const float* __restrict__ d0, const float* __restrict__ d1,
    unsigned short* __restrict__ t0, unsigned short* __restrict__ t1,
    float* __restrict__ o0, float* __restrict__ o1) {
  const float* D = blockIdx.y ? d1 : d0;
  unsigned short* T = blockIdx.y ? t1 : t0;
  float* O = blockIdx.y ? o1 : o0;
  const int n0 = blockIdx.x * 64;
  const int t = threadIdx.x;
  __shared__ __align__(16) unsigned short L[64 * 136];
#pragma unroll
  for (int i = 0; i < 8; ++i) {
    int idx = t + i * 256;
    int c = idx >> 4, nj = (idx & 15) * 4;
    float4 v = *(const float4*)&D[(size_t)c * NN + n0 + nj];
    *(float4*)&O[(size_t)c * NN + n0 + nj] = v;
    L[(nj + 0) * 136 + c] = (unsigned short)f2bf(v.x);
    L[(nj + 1) * 136 + c] = (unsigned short)f2bf(v.y);
    L[(nj + 2) * 136 + c] = (unsigned short)f2bf(v.z);
    L[(nj + 3) * 136 + c] = (unsigned short)f2bf(v.w);
  }
  __syncthreads();
#pragma unroll
  for (int i = 0; i < 4; ++i) {
    int idx = t + i * 256;
    int n = idx >> 4, cj = (idx & 15) * 8;
    uint4 v = *(const uint4*)&L[n * 136 + cj];
    *(uint4*)&T[(size_t)(n0 + n) * 128 + cj] = v;
  }
}

// ---------------------------------------------------------------------------
// Persistent fused kernel: all 6 layers, grid.sync() between phases.
// ---------------------------------------------------------------------------
struct KArgs {
  const float *bq, *bk, *bv, *b2;
  float *out0, *out1, *Sg0, *Sg1, *b1m;
  unsigned short *dT0, *dT1, *Qb0, *Qb1, *Kt0, *Kt1, *Vb0, *Vb1;
  unsigned short *mgT0, *mgT1, *HT0, *HT1;
  const unsigned short *Wqkv, *Wb2, *Wmix;
};

// bf16 MFMA GEMM tile, 64M x 64N, 4 waves (wave w: 16 n), K-step 32.
// Modes: 0=Q scaled [h][32d][n]  1=K [h][n][32d]  2=V [h][32d][n]
//        4=mlp2 (normalize+relu staging, fp32 residual += Cf, bf16 Cb)
//        5=mlp1 (bf16 out_T [n][ldc] + per-channel sum/ssq atomics into Cf)
__device__ __forceinline__ void gemm_tile(
    const unsigned short* __restrict__ Aw, const float* __restrict__ bias,
    const unsigned short* __restrict__ B1, const unsigned short* __restrict__ B2,
    unsigned short* __restrict__ Cb, float* __restrict__ Cf,
    const float* __restrict__ Sp,
    int K, int ldb, int ldc, int mode, int bm, int bn,
    unsigned short* SM, int t) {
  const int w = t >> 6, lane = t & 63;
  const int col = lane & 15, Qd = lane >> 4;
  unsigned short* Ws = SM;              // 64*40 shorts
  unsigned short* Xs = SM + 2560;       // 64*40 shorts
  float* fb = (float*)(SM + 5120);
  float* meanL = fb;                    // 256
  float* rstdL = fb + 256;              // 256
  float* swS = fb + 512;                // 4*64
  float* swQ = fb + 768;                // 4*64

  if (mode == 4) {
    float s = Sp[t * 2], ss = Sp[t * 2 + 1];
    float mean = s * (1.0f / NN);
    float var = fmaxf(ss * (1.0f / NN) - mean * mean, 0.f);
    meanL[t] = mean;
    rstdL[t] = rsqrtf(var + 1e-5f);
  }

  f32x4 acc[4];
#pragma unroll
  for (int mt = 0; mt < 4; ++mt) acc[mt] = (f32x4){0.f, 0.f, 0.f, 0.f};

  for (int k0 = 0; k0 < K; k0 += 32) {
    __syncthreads();
    {
      int row = t >> 2, ko = (t & 3) * 8;
      *(uint4*)&Ws[row * 40 + ko] =
          *(const uint4*)&Aw[(size_t)(bm + row) * K + k0 + ko];
      const unsigned short* Bp = B1;
      int kk0 = k0;
      if (B2 && k0 >= 128) { Bp = B2; kk0 = k0 - 128; }
      uint4 v = *(const uint4*)&Bp[(size_t)(bn + row) * ldb + kk0 + ko];
      if (mode == 4) {
        union { uint4 q; unsigned short us[8]; } u;
        u.q = v;
#pragma unroll
        for (int j = 0; j < 8; ++j) {
          int k = k0 + ko + j;
          float x = bf2f(u.us[j]);
          x = fmaxf((x - meanL[k]) * rstdL[k], 0.f);
          u.us[j] = (unsigned short)f2bf(x);
        }
        v = u.q;
      }
      *(uint4*)&Xs[row * 40 + ko] = v;
    }
    __syncthreads();
    bf16x8 bfr = *(const bf16x8*)&Xs[(w * 16 + col) * 40 + Qd * 8];
#pragma unroll
    for (int mt = 0; mt < 4; ++mt) {
      bf16x8 af = *(const bf16x8*)&Ws[(mt * 16 + col) * 40 + Qd * 8];
      acc[mt] = __builtin_amdgcn_mfma_f32_16x16x32_bf16(af, bfr, acc[mt], 0, 0, 0);
    }
  }

  const int n = bn + w * 16 + col;
#pragma unroll
  for (int mt = 0; mt < 4; ++mt) {
    const int c0 = bm + mt * 16 + Qd * 4;
    const float b0 = bias[c0], b1v = bias[c0 + 1];
    const float b2v = bias[c0 + 2], b3v = bias[c0 + 3];
    f32x4 a = acc[mt];
    float v0 = a[0] + b0, v1 = a[1] + b1v, v2 = a[2] + b2v, v3 = a[3] + b3v;
    if (mode <= 2) {
      if (mode == 0) {
        const float sc = 0.17677669529663687f;
        v0 *= sc; v1 *= sc; v2 *= sc; v3 *= sc;
      }
      const int d = c0 >> 2;
      if (mode == 1) {
        Cb[((size_t)0 * NN + n) * 32 + d] = (unsigned short)f2bf(v0);
        Cb[((size_t)1 * NN + n) * 32 + d] = (unsigned short)f2bf(v1);
        Cb[((size_t)2 * NN + n) * 32 + d] = (unsigned short)f2bf(v2);
        Cb[((size_t)3 * NN + n) * 32 + d] = (unsigned short)f2bf(v3);
      } else {
        Cb[(size_t)(0 * 32 + d) * NN + n] = (unsigned short)f2bf(v0);
        Cb[(size_t)(1 * 32 + d) * NN + n] = (unsigned short)f2bf(v1);
        Cb[(size_t)(2 * 32 + d) * NN + n] = (unsigned short)f2bf(v2);
        Cb[(size_t)(3 * 32 + d) * NN + n] = (unsigned short)f2bf(v3);
      }
    } else if (mode == 5) {
      uint2 pv = { pk2(v0, v1), pk2(v2, v3) };
      *(uint2*)&Cb[(size_t)n * ldc + c0] = pv;
      float sA[4] = {v0, v1, v2, v3};
      float sQ[4] = {v0 * v0, v1 * v1, v2 * v2, v3 * v3};
#pragma unroll
      for (int r = 0; r < 4; ++r) {
#pragma unroll
        for (int off = 1; off < 16; off <<= 1) {
          sA[r] += __shfl_xor(sA[r], off);
          sQ[r] += __shfl_xor(sQ[r], off);
        }
      }
      if (col == 0) {
#pragma unroll
        for (int r = 0; r < 4; ++r) {
          swS[w * 64 + mt * 16 + Qd * 4 + r] = sA[r];
          swQ[w * 64 + mt * 16 + Qd * 4 + r] = sQ[r];
        }
      }
    } else {  // mode 4
      float o0 = Cf[(size_t)(c0 + 0) * NN + n] + v0;
      float o1 = Cf[(size_t)(c0 + 1) * NN + n] + v1;
      float o2 = Cf[(size_t)(c0 + 2) * NN + n] + v2;
      float o3 = Cf[(size_t)(c0 + 3) * NN + n] + v3;
      Cf[(size_t)(c0 + 0) * NN + n] = o0;
      Cf[(size_t)(c0 + 1) * NN + n] = o1;
      Cf[(size_t)(c0 + 2) * NN + n] = o2;
      Cf[(size_t)(c0 + 3) * NN + n] = o3;
      uint2 pv = { pk2(o0, o1), pk2(o2, o3) };
      *(uint2*)&Cb[(size_t)n * ldc + c0] = pv;
    }
  }
  if (mode == 5) {
    __syncthreads();
    if (t < 64) {
      float a = swS[t] + swS[64 + t] + swS[128 + t] + swS[192 + t];
      float b = swQ[t] + swQ[64 + t] + swQ[128 + t] + swQ[192 + t];
      atomicAdd(&Cf[(bm + t) * 2], a);
      atomicAdd(&Cf[(bm + t) * 2 + 1], b);
    }
  }
}

// MFMA flash attention job (identical math to R6's attn kernel).
__device__ __forceinline__ void attn_job(const KArgs& A, int l, int job,
                                         unsigned short* SM, int t) {
  const int z = job >> 6;
  const int desc = z >> 2, h = z & 3;
  const int cross = l & 1;
  const int wid = t >> 6, lane = t & 63;
  const int col = lane & 15, Qd = lane >> 4;
  const int qsub = wid & 1, half = wid >> 1;
  const int qb = (job & 63) * 32;
  const int q0 = qb + qsub * 16;

  const unsigned short* Qb = desc ? A.Qb1 : A.Qb0;
  const int s = cross ? (1 - desc) : desc;
  const unsigned short* Kt = s ? A.Kt1 : A.Kt0;
  const unsigned short* Vb = s ? A.Vb1 : A.Vb0;

  unsigned short* KtL = SM + half * 4864;
  unsigned short* VL = SM + half * 4864 + 2560;
  unsigned short* PL = SM + 9728 + wid * 640;

  bf16x8 bq;
  {
    union { unsigned short u[8]; bf16x8 v; } tmp;
#pragma unroll
    for (int j = 0; j < 8; ++j)
      tmp.u[j] = Qb[(size_t)(h * 32 + Qd * 8 + j) * NN + q0 + col];
    bq = tmp.v;
  }

  f32x4 o[2];
  o[0] = (f32x4){0.f, 0.f, 0.f, 0.f};
  o[1] = (f32x4){0.f, 0.f, 0.f, 0.f};
  float m = -1e30f, l2 = 0.f;

  for (int it = 0; it < 16; ++it) {
    __syncthreads();
    {
      const int key = t >> 2, d8 = (t & 3) * 8;
      *(uint4*)&SM[key * 40 + d8] =
          *(const uint4*)&Kt[((size_t)h * NN + it * 64 + key) * 32 + d8];
      *(uint4*)&SM[4864 + key * 40 + d8] =
          *(const uint4*)&Kt[((size_t)h * NN + 1024 + it * 64 + key) * 32 + d8];
      const int dv = t >> 3, c8 = (t & 7) * 8;
      *(uint4*)&SM[2560 + dv * 72 + c8] =
          *(const uint4*)&Vb[(size_t)(h * 32 + dv) * NN + it * 64 + c8];
      *(uint4*)&SM[7424 + dv * 72 + c8] =
          *(const uint4*)&Vb[(size_t)(h * 32 + dv) * NN + 1024 + it * 64 + c8];
    }
    __syncthreads();
#pragma unroll
    for (int sub = 0; sub < 2; ++sub) {
      bf16x8 aK0 = *(const bf16x8*)&KtL[(sub * 32 + col) * 40 + Qd * 8];
      bf16x8 aK1 = *(const bf16x8*)&KtL[(sub * 32 + 16 + col) * 40 + Qd * 8];
      bf16x8 av0 = *(const bf16x8*)&VL[col * 72 + sub * 32 + Qd * 8];
      bf16x8 av1 = *(const bf16x8*)&VL[(16 + col) * 72 + sub * 32 + Qd * 8];
      f32x4 zacc = {0.f, 0.f, 0.f, 0.f};
      f32x4 s0 = __builtin_amdgcn_mfma_f32_16x16x32_bf16(aK0, bq, zacc, 0, 0, 0);
      f32x4 s1 = __builtin_amdgcn_mfma_f32_16x16x32_bf16(aK1, bq, zacc, 0, 0, 0);
      float cm = fmaxf(fmaxf(fmaxf(s0[0], s0[1]), fmaxf(s0[2], s0[3])),
                       fmaxf(fmaxf(s1[0], s1[1]), fmaxf(s1[2], s1[3])));
      cm = fmaxf(cm, __shfl_xor(cm, 16));
      cm = fmaxf(cm, __shfl_xor(cm, 32));
      const float mn = fmaxf(m, cm);
      const float alpha = __expf(m - mn);
      m = mn;
      float p00 = __expf(s0[0] - mn), p01 = __expf(s0[1] - mn);
      float p02 = __expf(s0[2] - mn), p03 = __expf(s0[3] - mn);
      float p10 = __expf(s1[0] - mn), p11 = __expf(s1[1] - mn);
      float p12 = __expf(s1[2] - mn), p13 = __expf(s1[3] - mn);
      float us = (p00 + p01) + (p02 + p03) + (p10 + p11) + (p12 + p13);
      us += __shfl_xor(us, 16);
      us += __shfl_xor(us, 32);
      l2 = l2 * alpha + us;
      uint2 w0 = { pk2(p00, p01), pk2(p02, p03) };
      uint2 w1 = { pk2(p10, p11), pk2(p12, p13) };
      *(uint2*)&PL[col * 40 + Qd * 4] = w0;
      *(uint2*)&PL[col * 40 + 16 + Qd * 4] = w1;
      __threadfence_block();
      bf16x8 pb = *(const bf16x8*)&PL[col * 40 + Qd * 8];
      o[0] = o[0] * alpha;
      o[1] = o[1] * alpha;
      o[0] = __builtin_amdgcn_mfma_f32_16x16x32_bf16(av0, pb, o[0], 0, 0, 0);
      o[1] = __builtin_amdgcn_mfma_f32_16x16x32_bf16(av1, pb, o[1], 0, 0, 0);
      __threadfence_block();
    }
  }

  __syncthreads();
  float* fS = (float*)SM;
#pragma unroll
  for (int h2 = 0; h2 < 2; ++h2) {
    *(float4*)&fS[wid * 512 + col * 32 + h2 * 16 + Qd * 4] =
        make_float4(o[h2][0], o[h2][1], o[h2][2], o[h2][3]);
  }
  if (Qd == 0) {
    fS[2048 + wid * 16 + col] = m;
    fS[2112 + wid * 16 + col] = l2;
  }
  __syncthreads();
  {
    const int ql = t & 31, dg = t >> 5;
    const int q16 = ql & 15, qs = ql >> 4;
    const int wA = qs, wB = 2 + qs;
    float m0 = fS[2048 + wA * 16 + q16], m1 = fS[2048 + wB * 16 + q16];
    float l0 = fS[2112 + wA * 16 + q16], l1 = fS[2112 + wB * 16 + q16];
    float M = fmaxf(m0, m1);
    float w0 = __expf(m0 - M), w1 = __expf(m1 - M);
    float inv = 1.0f / (w0 * l0 + w1 * l1);
    unsigned short* T = desc ? A.mgT1 : A.mgT0;
    const int q = qb + ql;
#pragma unroll
    for (int r = 0; r < 4; ++r) {
      int d = dg * 4 + r;
      float v = (w0 * fS[wA * 512 + q16 * 32 + d] + w1 * fS[wB * 512 + q16 * 32 + d]) * inv;
      T[(size_t)q * 128 + d * 4 + h] = (unsigned short)f2bf(v);
    }
  }
}

__global__ __launch_bounds__(256, 2) void fused_layers_kernel(KArgs A) {
  cg::grid_group grid = cg::this_grid();
  __shared__ __align__(16) unsigned short SM[12288];
  const int t = threadIdx.x;
  const int bid = blockIdx.x;
  const int G = gridDim.x;

  for (int l = 0; l < NL; ++l) {
    // ---- phase 1: QKV (384 jobs: 6 ops x 2 bm x 32 bn) ----
    for (int j = bid; j < 384; j += G) {
      const int opk = j >> 6, rem = j & 63;
      const int bn = (rem >> 1) * 64, bm = (rem & 1) * 64;
      const int dsc = opk & 1, kind = opk >> 1;
      const unsigned short* wA = A.Wqkv + kind * 98304 + l * 16384;
      const float* bias = (kind == 0 ? A.bq : kind == 1 ? A.bk : A.bv) + l * 128;
      const unsigned short* B1 = dsc ? A.dT1 : A.dT0;
      unsigned short* Cb = (kind == 0) ? (dsc ? A.Qb1 : A.Qb0)
                         : (kind == 1) ? (dsc ? A.Kt1 : A.Kt0)
                                       : (dsc ? A.Vb1 : A.Vb0);
      gemm_tile(wA, bias, B1, nullptr, Cb, nullptr, nullptr,
                128, 128, 0, kind, bm, bn, SM, t);
    }
    if (bid == 448) {
      A.Sg0[t] = 0.f; A.Sg0[t + 256] = 0.f;
      A.Sg1[t] = 0.f; A.Sg1[t + 256] = 0.f;
    }
    grid.sync();
    // ---- phase 2: attention (512 jobs) ----
    attn_job(A, l, bid, SM, t);
    grid.sync();
    // ---- phase 3: mlp1 (256 jobs: 2 desc x 4 bm x 32 bn) ----
    for (int j = bid; j < 256; j += G) {
      const int dsc = j & 1, rem = j >> 1;
      const int bn = (rem & 31) * 64, bm = (rem >> 5) * 64;
      gemm_tile(A.Wmix + l * 65536, A.b1m + l * 256,
                dsc ? A.dT1 : A.dT0, dsc ? A.mgT1 : A.mgT0,
                dsc ? A.HT1 : A.HT0, dsc ? A.Sg1 : A.Sg0, nullptr,
                256, 128, 256, 5, bm, bn, SM, t);
    }
    grid.sync();
    // ---- phase 4: mlp2 (128 jobs: 2 desc x 2 bm x 32 bn) ----
    for (int j = bid; j < 128; j += G) {
      const int dsc = j & 1, rem = j >> 1;
      const int bn = (rem & 31) * 64, bm = (rem >> 5) * 64;
      gemm_tile(A.Wb2 + l * 32768, A.b2 + l * 128,
                dsc ? A.HT1 : A.HT0, nullptr,
                dsc ? A.dT1 : A.dT0, dsc ? A.out1 : A.out0, dsc ? A.Sg1 : A.Sg0,
                256, 256, 128, 4, bm, bn, SM, t);
    }
    grid.sync();
  }
}

// ---------------------------------------------------------------------------
extern "C" void kernel_launch(void* const* d_in, const int* in_sizes, int n_in,
                              void* d_out, int out_size, void* d_ws, size_t ws_size,
                              hipStream_t stream) {
  const float* desc0 = (const float*)d_in[0];
  const float* desc1 = (const float*)d_in[1];
  const float* Wq = (const float*)d_in[2];
  const float* bq = (const float*)d_in[3];
  const float* Wk = (const float*)d_in[4];
  const float* bk = (const float*)d_in[5];
  const float* Wv = (const float*)d_in[6];
  const float* bv = (const float*)d_in[7];
  const float* Wm = (const float*)d_in[8];
  const float* bmv = (const float*)d_in[9];
  const float* W1 = (const float*)d_in[10];
  const float* b1 = (const float*)d_in[11];
  const float* W2 = (const float*)d_in[12];
  const float* b2 = (const float*)d_in[13];

  float* out0 = (float*)d_out;
  float* out1 = out0 + (size_t)DDIM * NN;

  float* fws = (float*)d_ws;
  float* Sg0 = fws;                    // 512
  float* Sg1 = Sg0 + 512;              // 512
  float* b1m = Sg1 + 512;              // 1536
  unsigned short* uws = (unsigned short*)(b1m + 1536);
  unsigned short* dT0 = uws;                     // 262144 each
  unsigned short* dT1 = uws + 1 * 262144;
  unsigned short* Qb0 = uws + 2 * 262144;
  unsigned short* Qb1 = uws + 3 * 262144;
  unsigned short* Kt0 = uws + 4 * 262144;
  unsigned short* Kt1 = uws + 5 * 262144;
  unsigned short* Vb0 = uws + 6 * 262144;
  unsigned short* Vb1 = uws + 7 * 262144;
  unsigned short* mgT0 = uws + 8 * 262144;
  unsigned short* mgT1 = uws + 9 * 262144;
  unsigned short* HT0 = uws + 10 * 262144;       // 524288
  unsigned short* HT1 = HT0 + 524288;            // 524288
  unsigned short* Wqkv = HT1 + 524288;           // 294912
  unsigned short* Wb2 = Wqkv + 294912;           // 196608
  unsigned short* Wmix = Wb2 + 196608;           // 393216

  wcast_kernel<<<672, 256, 0, stream>>>(Wq, Wk, Wv, W1, W2, Wqkv, Wb2, Wmix);
  wfuse_kernel<<<dim3(2, 4, 6), 256, 0, stream>>>(W1, Wm, Wmix, bmv, b1, b1m);
  desc_cast_kernel<<<dim3(32, 2), 256, 0, stream>>>(desc0, desc1, dT0, dT1, out0, out1);

  KArgs ka;
  ka.bq = bq; ka.bk = bk; ka.bv = bv; ka.b2 = b2;
  ka.out0 = out0; ka.out1 = out1; ka.Sg0 = Sg0; ka.Sg1 = Sg1; ka.b1m = b1m;
  ka.dT0 = dT0; ka.dT1 = dT1; ka.Qb0 = Qb0; ka.Qb1 = Qb1;
  ka.Kt0 = Kt0; ka.Kt1 = Kt1; ka.Vb0 = Vb0; ka.Vb1 = Vb1;
  ka.mgT0 = mgT0; ka.mgT1 = mgT1; ka.HT0 = HT0; ka.HT1 = HT1;
  ka.Wqkv = Wqkv; ka.Wb2 = Wb2; ka.Wmix = Wmix;
  void* params[] = { (void*)&ka };
  (void)hipLaunchCooperativeKernel((const void*)fused_layers_kernel,
                                   dim3(512), dim3(256), params, 0, stream);
}

// Round 8
// 447.391 us; speedup vs baseline: 4.0699x; 4.0699x over previous
//
#include <hip/hip_runtime.h>

#define NN 2048
#define DDIM 128
#define NHEAD 4
#define DH 32
#define NL 6

typedef __attribute__((ext_vector_type(8))) __bf16 bf16x8;
typedef __attribute__((ext_vector_type(4))) float f32x4;

__device__ __forceinline__ unsigned int f2bf(float x) {
  unsigned int u = __float_as_uint(x);
  u += 0x7fff + ((u >> 16) & 1);   // RNE
  return u >> 16;
}
__device__ __forceinline__ unsigned int pk2(float a, float b) {
  return f2bf(a) | (f2bf(b) << 16);
}
__device__ __forceinline__ float bf2f(unsigned short u) {
  return __uint_as_float(((unsigned int)u) << 16);
}

// ---------------------------------------------------------------------------
// Weight cast fp32->bf16 (unchanged from R6).
// ---------------------------------------------------------------------------
__global__ __launch_bounds__(256) void wcast_kernel(
    const float* __restrict__ Wq, const float* __restrict__ Wk,
    const float* __restrict__ Wv, const float* __restrict__ W1,
    const float* __restrict__ W2,
    unsigned short* __restrict__ Wqkv, unsigned short* __restrict__ Wb2,
    unsigned short* __restrict__ Wmix) {
  int idx = (blockIdx.x * 256 + threadIdx.x) * 4;
  if (idx >= 688128) return;
  const float* src; unsigned short* dst; int soff, doff;
  if (idx < 98304)       { src = Wq; soff = idx; dst = Wqkv; doff = idx; }
  else if (idx < 196608) { src = Wk; soff = idx - 98304; dst = Wqkv; doff = idx; }
  else if (idx < 294912) { src = Wv; soff = idx - 196608; dst = Wqkv; doff = idx; }
  else if (idx < 491520) { src = W2; soff = idx - 294912; dst = Wb2; doff = soff; }
  else {
    int f = idx - 491520;
    int l = f >> 15, rem = f & 32767;
    int i = rem >> 7, c = rem & 127;
    src = W1; soff = (l << 16) + (i << 8) + c;
    dst = Wmix; doff = (l << 16) + (i << 8) + c;
  }
  float4 v = *(const float4*)&src[soff];
  uint2 p = { pk2(v.x, v.y), pk2(v.z, v.w) };
  *(uint2*)&dst[doff] = p;
}

// ---------------------------------------------------------------------------
// Wfuse + b1 fold (unchanged from R6).
// ---------------------------------------------------------------------------
__global__ __launch_bounds__(256) void wfuse_kernel(
    const float* __restrict__ W1, const float* __restrict__ Wm,
    unsigned short* __restrict__ Wmix,
    const float* __restrict__ bmv, const float* __restrict__ b1,
    float* __restrict__ b1m) {
  const int l = blockIdx.z;
  const int bj = blockIdx.x * 64;
  const int bi = blockIdx.y * 64;
  __shared__ float Ws[32][65];
  __shared__ float Xs[32][64];
  const int t = threadIdx.x;
  const int ti = (t >> 4) << 2;
  const int tj = (t & 15) << 2;
  float acc[4][4] = {{0.f}};
  for (int k0 = 0; k0 < 128; k0 += 32) {
#pragma unroll
    for (int i = 0; i < 8; ++i) {
      int e = t + i * 256;
      int ii = e >> 5, kk = e & 31;
      Ws[kk][ii] = W1[(size_t)(l << 16) + (bi + ii) * 256 + 128 + k0 + kk];
    }
#pragma unroll
    for (int i = 0; i < 2; ++i) {
      int e = t + i * 256;
      int r = e >> 4, c4 = e & 15;
      *(float4*)&Xs[r][c4 * 4] = *(const float4*)&Wm[(size_t)l * 16384 + (k0 + r) * 128 + bj + c4 * 4];
    }
    __syncthreads();
#pragma unroll
    for (int kk = 0; kk < 32; ++kk) {
      float a[4];
      a[0] = Ws[kk][ti]; a[1] = Ws[kk][ti + 1]; a[2] = Ws[kk][ti + 2]; a[3] = Ws[kk][ti + 3];
      float4 b4 = *(const float4*)&Xs[kk][tj];
      float bb[4] = {b4.x, b4.y, b4.z, b4.w};
#pragma unroll
      for (int i = 0; i < 4; ++i)
#pragma unroll
        for (int j = 0; j < 4; ++j) acc[i][j] += a[i] * bb[j];
    }
    __syncthreads();
  }
#pragma unroll
  for (int i = 0; i < 4; ++i) {
    uint2 p = { pk2(acc[i][0], acc[i][1]), pk2(acc[i][2], acc[i][3]) };
    *(uint2*)&Wmix[(size_t)(l << 16) + (bi + ti + i) * 256 + 128 + bj + tj] = p;
  }
  if (blockIdx.x == 0 && blockIdx.y == 0) {
    float a = b1[l * 256 + t];
    const float* wr = &W1[(size_t)(l << 16) + t * 256 + 128];
    const float* bp = &bmv[l * 128];
    for (int k = 0; k < 128; k += 4)
      a += wr[k] * bp[k] + wr[k + 1] * bp[k + 1] + wr[k + 2] * bp[k + 2] + wr[k + 3] * bp[k + 3];
    b1m[l * 256 + t] = a;
  }
}

// ---------------------------------------------------------------------------
// desc fp32 [c][n] -> desc_T bf16 [n][128] + fp32 residual copy (unchanged).
// ---------------------------------------------------------------------------
__global__ __launch_bounds__(256) void desc_cast_kernel(
    const float* __restrict__ d0, const float* __restrict__ d1,
    unsigned short* __restrict__ t0, unsigned short* __restrict__ t1,
    float* __restrict__ o0, float* __restrict__ o1) {
  const float* D = blockIdx.y ? d1 : d0;
  unsigned short* T = blockIdx.y ? t1 : t0;
  float* O = blockIdx.y ? o1 : o0;
  const int n0 = blockIdx.x * 64;
  const int t = threadIdx.x;
  __shared__ __align__(16) unsigned short L[64 * 136];
#pragma unroll
  for (int i = 0; i < 8; ++i) {
    int idx = t + i * 256;
    int c = idx >> 4, nj = (idx & 15) * 4;
    float4 v = *(const float4*)&D[(size_t)c * NN + n0 + nj];
    *(float4*)&O[(size_t)c * NN + n0 + nj] = v;
    L[(nj + 0) * 136 + c] = (unsigned short)f2bf(v.x);
    L[(nj + 1) * 136 + c] = (unsigned short)f2bf(v.y);
    L[(nj + 2) * 136 + c] = (unsigned short)f2bf(v.z);
    L[(nj + 3) * 136 + c] = (unsigned short)f2bf(v.w);
  }
  __syncthreads();
#pragma unroll
  for (int i = 0; i < 4; ++i) {
    int idx = t + i * 256;
    int n = idx >> 4, cj = (idx & 15) * 8;
    uint4 v = *(const uint4*)&L[n * 136 + cj];
    *(uint4*)&T[(size_t)(n0 + n) * 128 + cj] = v;
  }
}

// ---------------------------------------------------------------------------
// Unified bf16 MFMA GEMM (R6 structure). Tile 64M x 128N, 4 waves.
// Mode 0 scale now includes log2(e) so attention can use exp2 directly.
// ---------------------------------------------------------------------------
struct MOp {
  const unsigned short* A;   // bf16 W [M][K]
  const float* bias;         // [M]
  const unsigned short* B1;  // X_T [N][ldb]
  const unsigned short* B2;  // concat second half (k>=128) or null
  unsigned short* Cb;
  float* Cf;
  const float* Sp;           // accumulated stats (mode 4): [c*2],[c*2+1]
  int K, ldb, ldc, mode;
};
struct MOps8 { MOp op[8]; };

__global__ __launch_bounds__(256) void mfma_gemm_kernel(MOps8 P) {
  const MOp g = P.op[blockIdx.z];
  const int t = threadIdx.x;
  const int w = t >> 6, lane = t & 63;
  const int col = lane & 15, Qd = lane >> 4;
  const int bm = blockIdx.y * 64;
  const int bn = blockIdx.x * 128;

  __shared__ __align__(16) unsigned short Ws[64 * 40];
  __shared__ __align__(16) unsigned short Xs[128 * 40];
  __shared__ float meanL[256], rstdL[256];
  __shared__ float swS[4][64], swQ[4][64];

  if (g.mode == 4) {
    float s = g.Sp[t * 2], ss = g.Sp[t * 2 + 1];
    float mean = s * (1.0f / NN);
    float var = fmaxf(ss * (1.0f / NN) - mean * mean, 0.f);
    meanL[t] = mean;
    rstdL[t] = rsqrtf(var + 1e-5f);
  }
  if (g.mode == 0 && g.Cf && blockIdx.x == 0 && blockIdx.y == 0) {
    g.Cf[t] = 0.f;
    g.Cf[t + 256] = 0.f;
  }

  f32x4 acc[4][2];
#pragma unroll
  for (int mt = 0; mt < 4; ++mt)
#pragma unroll
    for (int nt = 0; nt < 2; ++nt) acc[mt][nt] = (f32x4){0.f, 0.f, 0.f, 0.f};

  for (int k0 = 0; k0 < g.K; k0 += 32) {
    __syncthreads();
    {
      int row = t >> 2, ko = (t & 3) * 8;
      *(uint4*)&Ws[row * 40 + ko] =
          *(const uint4*)&g.A[(size_t)(bm + row) * g.K + k0 + ko];
    }
    const unsigned short* Bp = g.B1;
    int kk0 = k0;
    if (g.B2 && k0 >= 128) { Bp = g.B2; kk0 = k0 - 128; }
#pragma unroll
    for (int i = 0; i < 2; ++i) {
      int idx = t + i * 256;
      int row = idx >> 2, ko = (idx & 3) * 8;
      uint4 v = *(const uint4*)&Bp[(size_t)(bn + row) * g.ldb + kk0 + ko];
      if (g.mode == 4) {
        union { uint4 q; unsigned short us[8]; } u;
        u.q = v;
#pragma unroll
        for (int j = 0; j < 8; ++j) {
          int k = k0 + ko + j;
          float x = bf2f(u.us[j]);
          x = fmaxf((x - meanL[k]) * rstdL[k], 0.f);
          u.us[j] = (unsigned short)f2bf(x);
        }
        v = u.q;
      }
      *(uint4*)&Xs[row * 40 + ko] = v;
    }
    __syncthreads();
    bf16x8 af[4], bfr[2];
#pragma unroll
    for (int mt = 0; mt < 4; ++mt)
      af[mt] = *(const bf16x8*)&Ws[(mt * 16 + col) * 40 + Qd * 8];
#pragma unroll
    for (int nt = 0; nt < 2; ++nt)
      bfr[nt] = *(const bf16x8*)&Xs[(w * 32 + nt * 16 + col) * 40 + Qd * 8];
#pragma unroll
    for (int mt = 0; mt < 4; ++mt)
#pragma unroll
      for (int nt = 0; nt < 2; ++nt)
        acc[mt][nt] = __builtin_amdgcn_mfma_f32_16x16x32_bf16(af[mt], bfr[nt], acc[mt][nt], 0, 0, 0);
  }

#pragma unroll
  for (int mt = 0; mt < 4; ++mt) {
    const int c0 = bm + mt * 16 + Qd * 4;
    const float b0 = g.bias[c0], b1 = g.bias[c0 + 1];
    const float b2 = g.bias[c0 + 2], b3 = g.bias[c0 + 3];
    float sA[4] = {0.f, 0.f, 0.f, 0.f}, sQ[4] = {0.f, 0.f, 0.f, 0.f};
#pragma unroll
    for (int nt = 0; nt < 2; ++nt) {
      const int n = bn + w * 32 + nt * 16 + col;
      f32x4 a = acc[mt][nt];
      float v0 = a[0] + b0, v1 = a[1] + b1, v2 = a[2] + b2, v3 = a[3] + b3;
      if (g.mode <= 2) {
        if (g.mode == 0) {
          // 1/sqrt(32) * log2(e): attention softmax runs in base-2 domain
          const float sc = 0.25503488f;
          v0 *= sc; v1 *= sc; v2 *= sc; v3 *= sc;
        }
        const int d = c0 >> 2;
        if (g.mode == 1) {
          g.Cb[((size_t)0 * NN + n) * 32 + d] = (unsigned short)f2bf(v0);
          g.Cb[((size_t)1 * NN + n) * 32 + d] = (unsigned short)f2bf(v1);
          g.Cb[((size_t)2 * NN + n) * 32 + d] = (unsigned short)f2bf(v2);
          g.Cb[((size_t)3 * NN + n) * 32 + d] = (unsigned short)f2bf(v3);
        } else {
          g.Cb[(size_t)(0 * 32 + d) * NN + n] = (unsigned short)f2bf(v0);
          g.Cb[(size_t)(1 * 32 + d) * NN + n] = (unsigned short)f2bf(v1);
          g.Cb[(size_t)(2 * 32 + d) * NN + n] = (unsigned short)f2bf(v2);
          g.Cb[(size_t)(3 * 32 + d) * NN + n] = (unsigned short)f2bf(v3);
        }
      } else if (g.mode == 5) {
        uint2 pv = { pk2(v0, v1), pk2(v2, v3) };
        *(uint2*)&g.Cb[(size_t)n * g.ldc + c0] = pv;
        sA[0] += v0; sA[1] += v1; sA[2] += v2; sA[3] += v3;
        sQ[0] += v0 * v0; sQ[1] += v1 * v1; sQ[2] += v2 * v2; sQ[3] += v3 * v3;
      } else {
        float* dp = g.Cf;
        float o0 = dp[(size_t)(c0 + 0) * NN + n] + v0;
        float o1 = dp[(size_t)(c0 + 1) * NN + n] + v1;
        float o2 = dp[(size_t)(c0 + 2) * NN + n] + v2;
        float o3 = dp[(size_t)(c0 + 3) * NN + n] + v3;
        dp[(size_t)(c0 + 0) * NN + n] = o0;
        dp[(size_t)(c0 + 1) * NN + n] = o1;
        dp[(size_t)(c0 + 2) * NN + n] = o2;
        dp[(size_t)(c0 + 3) * NN + n] = o3;
        uint2 pv = { pk2(o0, o1), pk2(o2, o3) };
        *(uint2*)&g.Cb[(size_t)n * 128 + c0] = pv;
      }
    }
    if (g.mode == 5) {
#pragma unroll
      for (int r = 0; r < 4; ++r) {
#pragma unroll
        for (int off = 1; off < 16; off <<= 1) {
          sA[r] += __shfl_xor(sA[r], off);
          sQ[r] += __shfl_xor(sQ[r], off);
        }
      }
      if (col == 0) {
#pragma unroll
        for (int r = 0; r < 4; ++r) {
          swS[w][mt * 16 + Qd * 4 + r] = sA[r];
          swQ[w][mt * 16 + Qd * 4 + r] = sQ[r];
        }
      }
    }
  }
  if (g.mode == 5) {
    __syncthreads();
    if (t < 64) {
      float a = swS[0][t] + swS[1][t] + swS[2][t] + swS[3][t];
      float b = swQ[0][t] + swQ[1][t] + swQ[2][t] + swQ[3][t];
      atomicAdd(&g.Cf[(bm + t) * 2], a);
      atomicAdd(&g.Cf[(bm + t) * 2 + 1], b);
    }
  }
}

// ---------------------------------------------------------------------------
// MFMA flash attention (bf16), WAVE-PRIVATE key quarters, barrier-free loop.
// Grid: (128 q-tiles of 16, 8 = desc*4+head). Block 256 = 4 waves.
// Wave wid: same 16 queries, keys [wid*512, wid*512+512), staged into its own
// LDS slice (no __syncthreads in the main loop; in-wave ds ordering via
// compiler lgkmcnt). Softmax in base-2 (Q pre-scaled by log2e/sqrt(DH)).
// 4-way LDS merge at the end writes mg_T bf16 [q][128] (channel = d*4+h).
// ---------------------------------------------------------------------------
__global__ __launch_bounds__(256, 4) void attn_mfma_kernel(
    const unsigned short* __restrict__ Qb0, const unsigned short* __restrict__ Kt0,
    const unsigned short* __restrict__ Vb0, const unsigned short* __restrict__ Qb1,
    const unsigned short* __restrict__ Kt1, const unsigned short* __restrict__ Vb1,
    unsigned short* __restrict__ mgT0, unsigned short* __restrict__ mgT1, int cross) {
  const int z = blockIdx.y, desc = z >> 2, h = z & 3;
  const int t = threadIdx.x;
  const int wid = t >> 6, lane = t & 63;
  const int col = lane & 15, Qd = lane >> 4;
  const int qb = blockIdx.x * 16;

  const unsigned short* Qb = desc ? Qb1 : Qb0;
  const int s = cross ? (1 - desc) : desc;
  const unsigned short* Kt = s ? Kt1 : Kt0;
  const unsigned short* Vb = s ? Vb1 : Vb0;

  // Per-wave slice (3200 shorts): KtW[32key][40] @0, VW[32d][40] @1280,
  // PW[16q][40] @2560. Total 12800 shorts = 25.6 KB -> 4 blocks/CU.
  __shared__ __align__(16) unsigned short SM[12800];
  unsigned short* KtW = SM + wid * 3200;
  unsigned short* VW = SM + wid * 3200 + 1280;
  unsigned short* PW = SM + wid * 3200 + 2560;

  bf16x8 bq;
  {
    union { unsigned short u[8]; bf16x8 v; } tmp;
#pragma unroll
    for (int j = 0; j < 8; ++j)
      tmp.u[j] = Qb[(size_t)(h * 32 + Qd * 8 + j) * NN + qb + col];
    bq = tmp.v;
  }

  f32x4 o0 = {0.f, 0.f, 0.f, 0.f}, o1 = {0.f, 0.f, 0.f, 0.f};
  float m = -1e30f, l = 0.f;

  const int kq = wid * 512;
  for (int it = 0; it < 16; ++it) {
    const int k0 = kq + it * 32;
    // wave-private staging: 32 keys of K^T + 32x32 V tile
#pragma unroll
    for (int jj = 0; jj < 2; ++jj) {
      int e = lane + jj * 64;
      int r4 = e >> 2, seg = (e & 3) * 8;
      *(uint4*)&KtW[r4 * 40 + seg] =
          *(const uint4*)&Kt[((size_t)h * NN + k0 + r4) * 32 + seg];
      *(uint4*)&VW[r4 * 40 + seg] =
          *(const uint4*)&Vb[(size_t)(h * 32 + r4) * NN + k0 + seg];
    }
    bf16x8 aK0 = *(const bf16x8*)&KtW[col * 40 + Qd * 8];
    bf16x8 aK1 = *(const bf16x8*)&KtW[(16 + col) * 40 + Qd * 8];
    bf16x8 av0 = *(const bf16x8*)&VW[col * 40 + Qd * 8];
    bf16x8 av1 = *(const bf16x8*)&VW[(16 + col) * 40 + Qd * 8];
    f32x4 z4 = {0.f, 0.f, 0.f, 0.f};
    f32x4 s0 = __builtin_amdgcn_mfma_f32_16x16x32_bf16(aK0, bq, z4, 0, 0, 0);
    f32x4 s1 = __builtin_amdgcn_mfma_f32_16x16x32_bf16(aK1, bq, z4, 0, 0, 0);
    float cm = fmaxf(fmaxf(fmaxf(s0[0], s0[1]), fmaxf(s0[2], s0[3])),
                     fmaxf(fmaxf(s1[0], s1[1]), fmaxf(s1[2], s1[3])));
    cm = fmaxf(cm, __shfl_xor(cm, 16));
    cm = fmaxf(cm, __shfl_xor(cm, 32));
    const float mn = fmaxf(m, cm);
    const float alpha = exp2f(m - mn);
    m = mn;
    float p00 = exp2f(s0[0] - mn), p01 = exp2f(s0[1] - mn);
    float p02 = exp2f(s0[2] - mn), p03 = exp2f(s0[3] - mn);
    float p10 = exp2f(s1[0] - mn), p11 = exp2f(s1[1] - mn);
    float p12 = exp2f(s1[2] - mn), p13 = exp2f(s1[3] - mn);
    float us = (p00 + p01) + (p02 + p03) + (p10 + p11) + (p12 + p13);
    us += __shfl_xor(us, 16);
    us += __shfl_xor(us, 32);
    l = l * alpha + us;
    uint2 w0 = { pk2(p00, p01), pk2(p02, p03) };
    uint2 w1 = { pk2(p10, p11), pk2(p12, p13) };
    *(uint2*)&PW[col * 40 + Qd * 4] = w0;
    *(uint2*)&PW[col * 40 + 16 + Qd * 4] = w1;
    bf16x8 pb = *(const bf16x8*)&PW[col * 40 + Qd * 8];
    o0 = o0 * alpha;
    o1 = o1 * alpha;
    o0 = __builtin_amdgcn_mfma_f32_16x16x32_bf16(av0, pb, o0, 0, 0, 0);
    o1 = __builtin_amdgcn_mfma_f32_16x16x32_bf16(av1, pb, o1, 0, 0, 0);
  }

  // ---- 4-way merge across key quarters via LDS ----
  __syncthreads();
  float* fS = (float*)SM;   // o: [wid][16q][36 (32d+pad)] = 4*576; m@2304; l@2368
  *(float4*)&fS[wid * 576 + col * 36 + Qd * 4] =
      make_float4(o0[0], o0[1], o0[2], o0[3]);
  *(float4*)&fS[wid * 576 + col * 36 + 16 + Qd * 4] =
      make_float4(o1[0], o1[1], o1[2], o1[3]);
  if (Qd == 0) {
    fS[2304 + wid * 16 + col] = m;
    fS[2368 + wid * 16 + col] = l;
  }
  __syncthreads();
  {
    const int q16 = t >> 4, dg = t & 15;
    float m0 = fS[2304 + q16], m1 = fS[2304 + 16 + q16];
    float m2 = fS[2304 + 32 + q16], m3 = fS[2304 + 48 + q16];
    float M = fmaxf(fmaxf(m0, m1), fmaxf(m2, m3));
    float w0 = exp2f(m0 - M), w1 = exp2f(m1 - M);
    float w2 = exp2f(m2 - M), w3 = exp2f(m3 - M);
    float L = w0 * fS[2368 + q16] + w1 * fS[2368 + 16 + q16] +
              w2 * fS[2368 + 32 + q16] + w3 * fS[2368 + 48 + q16];
    float inv = 1.0f / L;
    unsigned short* T = desc ? mgT1 : mgT0;
    const int q = qb + q16;
#pragma unroll
    for (int r = 0; r < 2; ++r) {
      int d = dg * 2 + r;
      float v = (w0 * fS[0 * 576 + q16 * 36 + d] + w1 * fS[1 * 576 + q16 * 36 + d] +
                 w2 * fS[2 * 576 + q16 * 36 + d] + w3 * fS[3 * 576 + q16 * 36 + d]) * inv;
      T[(size_t)q * 128 + d * 4 + h] = (unsigned short)f2bf(v);
    }
  }
}

// ---------------------------------------------------------------------------
extern "C" void kernel_launch(void* const* d_in, const int* in_sizes, int n_in,
                              void* d_out, int out_size, void* d_ws, size_t ws_size,
                              hipStream_t stream) {
  const float* desc0 = (const float*)d_in[0];
  const float* desc1 = (const float*)d_in[1];
  const float* Wq = (const float*)d_in[2];
  const float* bq = (const float*)d_in[3];
  const float* Wk = (const float*)d_in[4];
  const float* bk = (const float*)d_in[5];
  const float* Wv = (const float*)d_in[6];
  const float* bv = (const float*)d_in[7];
  const float* Wm = (const float*)d_in[8];
  const float* bmv = (const float*)d_in[9];
  const float* W1 = (const float*)d_in[10];
  const float* b1 = (const float*)d_in[11];
  const float* W2 = (const float*)d_in[12];
  const float* b2 = (const float*)d_in[13];

  float* out0 = (float*)d_out;
  float* out1 = out0 + (size_t)DDIM * NN;

  float* fws = (float*)d_ws;
  float* Sg0 = fws;                    // 512
  float* Sg1 = Sg0 + 512;              // 512
  float* b1m = Sg1 + 512;              // 1536
  unsigned short* uws = (unsigned short*)(b1m + 1536);
  unsigned short* dT0 = uws;                     // 262144 each
  unsigned short* dT1 = uws + 1 * 262144;
  unsigned short* Qb0 = uws + 2 * 262144;
  unsigned short* Qb1 = uws + 3 * 262144;
  unsigned short* Kt0 = uws + 4 * 262144;
  unsigned short* Kt1 = uws + 5 * 262144;
  unsigned short* Vb0 = uws + 6 * 262144;
  unsigned short* Vb1 = uws + 7 * 262144;
  unsigned short* mgT0 = uws + 8 * 262144;
  unsigned short* mgT1 = uws + 9 * 262144;
  unsigned short* HT0 = uws + 10 * 262144;       // 524288
  unsigned short* HT1 = HT0 + 524288;            // 524288
  unsigned short* Wqkv = HT1 + 524288;           // 294912
  unsigned short* Wb2 = Wqkv + 294912;           // 196608
  unsigned short* Wmix = Wb2 + 196608;           // 393216

  wcast_kernel<<<672, 256, 0, stream>>>(Wq, Wk, Wv, W1, W2, Wqkv, Wb2, Wmix);
  wfuse_kernel<<<dim3(2, 4, 6), 256, 0, stream>>>(W1, Wm, Wmix, bmv, b1, b1m);
  desc_cast_kernel<<<dim3(32, 2), 256, 0, stream>>>(desc0, desc1, dT0, dT1, out0, out1);

  for (int l = 0; l < NL; ++l) {
    const int cross = l & 1;
    const unsigned short* wq = Wqkv + l * 16384;
    const unsigned short* wk = Wqkv + 98304 + l * 16384;
    const unsigned short* wv = Wqkv + 196608 + l * 16384;
    const unsigned short* wmx = Wmix + l * 65536;
    const unsigned short* w2 = Wb2 + l * 32768;
    const float* bqp = bq + (size_t)l * 128;
    const float* bkp = bk + (size_t)l * 128;
    const float* bvp = bv + (size_t)l * 128;
    const float* b1p = b1m + (size_t)l * 256;
    const float* b2p = b2 + (size_t)l * 128;

    MOps8 Pq = {};
    Pq.op[0] = {wq, bqp, dT0, nullptr, Qb0, Sg0, nullptr, 128, 128, 0, 0};
    Pq.op[1] = {wq, bqp, dT1, nullptr, Qb1, Sg1, nullptr, 128, 128, 0, 0};
    Pq.op[2] = {wk, bkp, dT0, nullptr, Kt0, nullptr, nullptr, 128, 128, 0, 1};
    Pq.op[3] = {wk, bkp, dT1, nullptr, Kt1, nullptr, nullptr, 128, 128, 0, 1};
    Pq.op[4] = {wv, bvp, dT0, nullptr, Vb0, nullptr, nullptr, 128, 128, 0, 2};
    Pq.op[5] = {wv, bvp, dT1, nullptr, Vb1, nullptr, nullptr, 128, 128, 0, 2};
    mfma_gemm_kernel<<<dim3(16, 2, 6), 256, 0, stream>>>(Pq);

    attn_mfma_kernel<<<dim3(128, 8), 256, 0, stream>>>(
        Qb0, Kt0, Vb0, Qb1, Kt1, Vb1, mgT0, mgT1, cross);

    MOps8 P1 = {};
    P1.op[0] = {wmx, b1p, dT0, mgT0, HT0, Sg0, nullptr, 256, 128, 256, 5};
    P1.op[1] = {wmx, b1p, dT1, mgT1, HT1, Sg1, nullptr, 256, 128, 256, 5};
    mfma_gemm_kernel<<<dim3(16, 4, 2), 256, 0, stream>>>(P1);

    MOps8 P2 = {};
    P2.op[0] = {w2, b2p, HT0, nullptr, dT0, out0, Sg0, 256, 256, 128, 4};
    P2.op[1] = {w2, b2p, HT1, nullptr, dT1, out1, Sg1, 256, 256, 128, 4};
    mfma_gemm_kernel<<<dim3(16, 2, 2), 256, 0, stream>>>(P2);
  }
}

// Round 9
// 425.032 us; speedup vs baseline: 4.2840x; 1.0526x over previous
//
#include <hip/hip_runtime.h>

#define NN 2048
#define DDIM 128
#define NHEAD 4
#define DH 32
#define NL 6

typedef __attribute__((ext_vector_type(8))) __bf16 bf16x8;
typedef __attribute__((ext_vector_type(4))) float f32x4;

__device__ __forceinline__ unsigned int f2bf(float x) {
  unsigned int u = __float_as_uint(x);
  u += 0x7fff + ((u >> 16) & 1);   // RNE
  return u >> 16;
}
__device__ __forceinline__ unsigned int pk2(float a, float b) {
  return f2bf(a) | (f2bf(b) << 16);
}
__device__ __forceinline__ float bf2f(unsigned short u) {
  return __uint_as_float(((unsigned int)u) << 16);
}

// ---------------------------------------------------------------------------
// Fused setup: one dispatch, 784 blocks.
//   0..671  : weight cast fp32->bf16 (Wqkv | Wb2 | Wmix low-k)
//   672..719: Wmix high-k = W1b @ Wm (fp32 acc) + b1 fold (block j0 i0)
//   720..783: desc transpose/cast + fp32 residual copy
// ---------------------------------------------------------------------------
__global__ __launch_bounds__(256) void setup_kernel(
    const float* __restrict__ Wq, const float* __restrict__ Wk,
    const float* __restrict__ Wv, const float* __restrict__ Wm,
    const float* __restrict__ W1, const float* __restrict__ W2,
    const float* __restrict__ bmv, const float* __restrict__ b1,
    const float* __restrict__ desc0, const float* __restrict__ desc1,
    unsigned short* __restrict__ Wqkv, unsigned short* __restrict__ Wb2,
    unsigned short* __restrict__ Wmix, float* __restrict__ b1m,
    unsigned short* __restrict__ dT0, unsigned short* __restrict__ dT1,
    float* __restrict__ o0, float* __restrict__ o1) {
  __shared__ __align__(16) unsigned char ARENA[17408];
  const int bid = blockIdx.x;
  const int t = threadIdx.x;

  if (bid < 672) {
    int idx = (bid * 256 + t) * 4;
    if (idx >= 688128) return;
    const float* src; unsigned short* dst; int soff, doff;
    if (idx < 98304)       { src = Wq; soff = idx; dst = Wqkv; doff = idx; }
    else if (idx < 196608) { src = Wk; soff = idx - 98304; dst = Wqkv; doff = idx; }
    else if (idx < 294912) { src = Wv; soff = idx - 196608; dst = Wqkv; doff = idx; }
    else if (idx < 491520) { src = W2; soff = idx - 294912; dst = Wb2; doff = soff; }
    else {
      int f = idx - 491520;
      int l = f >> 15, rem = f & 32767;
      int i = rem >> 7, c = rem & 127;
      src = W1; soff = (l << 16) + (i << 8) + c;
      dst = Wmix; doff = (l << 16) + (i << 8) + c;
    }
    float4 v = *(const float4*)&src[soff];
    uint2 p = { pk2(v.x, v.y), pk2(v.z, v.w) };
    *(uint2*)&dst[doff] = p;
  } else if (bid < 720) {
    const int b = bid - 672;
    const int jb = b & 1, ib = (b >> 1) & 3, l = b >> 3;
    const int bj = jb * 64, bi = ib * 64;
    float* Ws = (float*)ARENA;            // [32][65]
    float* Xs = (float*)ARENA + 2080;     // [32][64]
    const int ti = (t >> 4) << 2;
    const int tj = (t & 15) << 2;
    float acc[4][4] = {{0.f}};
    for (int k0 = 0; k0 < 128; k0 += 32) {
#pragma unroll
      for (int i = 0; i < 8; ++i) {
        int e = t + i * 256;
        int ii = e >> 5, kk = e & 31;
        Ws[kk * 65 + ii] = W1[(size_t)(l << 16) + (bi + ii) * 256 + 128 + k0 + kk];
      }
#pragma unroll
      for (int i = 0; i < 2; ++i) {
        int e = t + i * 256;
        int r = e >> 4, c4 = e & 15;
        *(float4*)&Xs[r * 64 + c4 * 4] =
            *(const float4*)&Wm[(size_t)l * 16384 + (k0 + r) * 128 + bj + c4 * 4];
      }
      __syncthreads();
#pragma unroll
      for (int kk = 0; kk < 32; ++kk) {
        float a[4];
        a[0] = Ws[kk * 65 + ti]; a[1] = Ws[kk * 65 + ti + 1];
        a[2] = Ws[kk * 65 + ti + 2]; a[3] = Ws[kk * 65 + ti + 3];
        float4 b4 = *(const float4*)&Xs[kk * 64 + tj];
        float bb[4] = {b4.x, b4.y, b4.z, b4.w};
#pragma unroll
        for (int i = 0; i < 4; ++i)
#pragma unroll
          for (int j = 0; j < 4; ++j) acc[i][j] += a[i] * bb[j];
      }
      __syncthreads();
    }
#pragma unroll
    for (int i = 0; i < 4; ++i) {
      uint2 p = { pk2(acc[i][0], acc[i][1]), pk2(acc[i][2], acc[i][3]) };
      *(uint2*)&Wmix[(size_t)(l << 16) + (bi + ti + i) * 256 + 128 + bj + tj] = p;
    }
    if (jb == 0 && ib == 0) {
      float a = b1[l * 256 + t];
      const float* wr = &W1[(size_t)(l << 16) + t * 256 + 128];
      const float* bp = &bmv[l * 128];
      for (int k = 0; k < 128; k += 4)
        a += wr[k] * bp[k] + wr[k + 1] * bp[k + 1] + wr[k + 2] * bp[k + 2] + wr[k + 3] * bp[k + 3];
      b1m[l * 256 + t] = a;
    }
  } else {
    const int b = bid - 720;
    const float* D = (b >> 5) ? desc1 : desc0;
    unsigned short* T = (b >> 5) ? dT1 : dT0;
    float* O = (b >> 5) ? o1 : o0;
    const int n0 = (b & 31) * 64;
    unsigned short* L = (unsigned short*)ARENA;   // [64][136]
#pragma unroll
    for (int i = 0; i < 8; ++i) {
      int idx = t + i * 256;
      int c = idx >> 4, nj = (idx & 15) * 4;
      float4 v = *(const float4*)&D[(size_t)c * NN + n0 + nj];
      *(float4*)&O[(size_t)c * NN + n0 + nj] = v;
      L[(nj + 0) * 136 + c] = (unsigned short)f2bf(v.x);
      L[(nj + 1) * 136 + c] = (unsigned short)f2bf(v.y);
      L[(nj + 2) * 136 + c] = (unsigned short)f2bf(v.z);
      L[(nj + 3) * 136 + c] = (unsigned short)f2bf(v.w);
    }
    __syncthreads();
#pragma unroll
    for (int i = 0; i < 4; ++i) {
      int idx = t + i * 256;
      int n = idx >> 4, cj = (idx & 15) * 8;
      uint4 v = *(const uint4*)&L[n * 136 + cj];
      *(uint4*)&T[(size_t)(n0 + n) * 128 + cj] = v;
    }
  }
}

// ---------------------------------------------------------------------------
// Direct-fragment bf16 MFMA GEMM: NO LDS staging, NO barriers in the K-loop.
// Both operands are fragment-contiguous in global memory:
//   A-frag = W[(m)*K + k0 + Qd*8], B-frag = X_T[n*ldb + k0 + Qd*8].
// Tile 64M x 64N, 4 waves (wave w: n = bn + w*16 + col), 4 m-frags.
// Modes: 0=Q scaled (also zeroes Sg via Cf at block 0,0)  1=K  2=V
//        4=mlp2 (normalize+relu B on the fly, fp32 residual += Cf, bf16 Cb)
//        5=mlp1 (bf16 out_T + per-channel sum/ssq atomics into Cf)
// ---------------------------------------------------------------------------
struct MOp {
  const unsigned short* A;
  const float* bias;
  const unsigned short* B1;
  const unsigned short* B2;
  unsigned short* Cb;
  float* Cf;
  const float* Sp;
  int ldb, ldc, mode;
};
struct MOps8 { MOp op[8]; };

template <int K>
__global__ __launch_bounds__(256) void gemm_direct_kernel(MOps8 P) {
  const MOp g = P.op[blockIdx.z];
  const int t = threadIdx.x;
  const int w = t >> 6, lane = t & 63;
  const int col = lane & 15, Qd = lane >> 4;
  const int bm = blockIdx.y * 64;
  const int bn = blockIdx.x * 64;

  __shared__ float meanL[256], rstdL[256];
  __shared__ float swS[4][64], swQ[4][64];

  if (g.mode == 4) {
    float s = g.Sp[t * 2], ss = g.Sp[t * 2 + 1];
    float mean = s * (1.0f / NN);
    float var = fmaxf(ss * (1.0f / NN) - mean * mean, 0.f);
    meanL[t] = mean;
    rstdL[t] = rsqrtf(var + 1e-5f);
  }
  if (g.mode == 0 && g.Cf && blockIdx.x == 0 && blockIdx.y == 0) {
    g.Cf[t] = 0.f;
    g.Cf[t + 256] = 0.f;
  }
  __syncthreads();

  const int n = bn + w * 16 + col;
  f32x4 acc[4];
#pragma unroll
  for (int mt = 0; mt < 4; ++mt) acc[mt] = (f32x4){0.f, 0.f, 0.f, 0.f};

#pragma unroll
  for (int k0 = 0; k0 < K; k0 += 32) {
    bf16x8 af[4];
#pragma unroll
    for (int mt = 0; mt < 4; ++mt)
      af[mt] = *(const bf16x8*)&g.A[(size_t)(bm + mt * 16 + col) * K + k0 + Qd * 8];
    const unsigned short* Bp = g.B1;
    int kk = k0;
    if (g.B2 && k0 >= 128) { Bp = g.B2; kk = k0 - 128; }
    uint4 v = *(const uint4*)&Bp[(size_t)n * g.ldb + kk + Qd * 8];
    if (g.mode == 4) {
      float4 mA = *(const float4*)&meanL[k0 + Qd * 8];
      float4 mB = *(const float4*)&meanL[k0 + Qd * 8 + 4];
      float4 rA = *(const float4*)&rstdL[k0 + Qd * 8];
      float4 rB = *(const float4*)&rstdL[k0 + Qd * 8 + 4];
      union { uint4 q; unsigned short us[8]; } u;
      u.q = v;
      float x0 = fmaxf((bf2f(u.us[0]) - mA.x) * rA.x, 0.f);
      float x1 = fmaxf((bf2f(u.us[1]) - mA.y) * rA.y, 0.f);
      float x2 = fmaxf((bf2f(u.us[2]) - mA.z) * rA.z, 0.f);
      float x3 = fmaxf((bf2f(u.us[3]) - mA.w) * rA.w, 0.f);
      float x4 = fmaxf((bf2f(u.us[4]) - mB.x) * rB.x, 0.f);
      float x5 = fmaxf((bf2f(u.us[5]) - mB.y) * rB.y, 0.f);
      float x6 = fmaxf((bf2f(u.us[6]) - mB.z) * rB.z, 0.f);
      float x7 = fmaxf((bf2f(u.us[7]) - mB.w) * rB.w, 0.f);
      u.q.x = pk2(x0, x1); u.q.y = pk2(x2, x3);
      u.q.z = pk2(x4, x5); u.q.w = pk2(x6, x7);
      v = u.q;
    }
    union { uint4 q; bf16x8 b; } bc;
    bc.q = v;
#pragma unroll
    for (int mt = 0; mt < 4; ++mt)
      acc[mt] = __builtin_amdgcn_mfma_f32_16x16x32_bf16(af[mt], bc.b, acc[mt], 0, 0, 0);
  }

#pragma unroll
  for (int mt = 0; mt < 4; ++mt) {
    const int c0 = bm + mt * 16 + Qd * 4;
    const float b0 = g.bias[c0], b1 = g.bias[c0 + 1];
    const float b2 = g.bias[c0 + 2], b3 = g.bias[c0 + 3];
    f32x4 a = acc[mt];
    float v0 = a[0] + b0, v1 = a[1] + b1, v2 = a[2] + b2, v3 = a[3] + b3;
    if (g.mode <= 2) {
      if (g.mode == 0) {
        // 1/sqrt(32) * log2(e) -> softmax in base-2 domain
        const float sc = 0.25503488f;
        v0 *= sc; v1 *= sc; v2 *= sc; v3 *= sc;
      }
      const int d = c0 >> 2;
      if (g.mode == 1) {
        g.Cb[((size_t)0 * NN + n) * 32 + d] = (unsigned short)f2bf(v0);
        g.Cb[((size_t)1 * NN + n) * 32 + d] = (unsigned short)f2bf(v1);
        g.Cb[((size_t)2 * NN + n) * 32 + d] = (unsigned short)f2bf(v2);
        g.Cb[((size_t)3 * NN + n) * 32 + d] = (unsigned short)f2bf(v3);
      } else {
        g.Cb[(size_t)(0 * 32 + d) * NN + n] = (unsigned short)f2bf(v0);
        g.Cb[(size_t)(1 * 32 + d) * NN + n] = (unsigned short)f2bf(v1);
        g.Cb[(size_t)(2 * 32 + d) * NN + n] = (unsigned short)f2bf(v2);
        g.Cb[(size_t)(3 * 32 + d) * NN + n] = (unsigned short)f2bf(v3);
      }
    } else if (g.mode == 5) {
      uint2 pv = { pk2(v0, v1), pk2(v2, v3) };
      *(uint2*)&g.Cb[(size_t)n * g.ldc + c0] = pv;
      float sA[4] = {v0, v1, v2, v3};
      float sQ[4] = {v0 * v0, v1 * v1, v2 * v2, v3 * v3};
#pragma unroll
      for (int r = 0; r < 4; ++r) {
#pragma unroll
        for (int off = 1; off < 16; off <<= 1) {
          sA[r] += __shfl_xor(sA[r], off);
          sQ[r] += __shfl_xor(sQ[r], off);
        }
      }
      if (col == 0) {
#pragma unroll
        for (int r = 0; r < 4; ++r) {
          swS[w][mt * 16 + Qd * 4 + r] = sA[r];
          swQ[w][mt * 16 + Qd * 4 + r] = sQ[r];
        }
      }
    } else {  // mode 4
      float* dp = g.Cf;
      float o0 = dp[(size_t)(c0 + 0) * NN + n] + v0;
      float o1 = dp[(size_t)(c0 + 1) * NN + n] + v1;
      float o2 = dp[(size_t)(c0 + 2) * NN + n] + v2;
      float o3 = dp[(size_t)(c0 + 3) * NN + n] + v3;
      dp[(size_t)(c0 + 0) * NN + n] = o0;
      dp[(size_t)(c0 + 1) * NN + n] = o1;
      dp[(size_t)(c0 + 2) * NN + n] = o2;
      dp[(size_t)(c0 + 3) * NN + n] = o3;
      uint2 pv = { pk2(o0, o1), pk2(o2, o3) };
      *(uint2*)&g.Cb[(size_t)n * g.ldc + c0] = pv;
    }
  }
  if (g.mode == 5) {
    __syncthreads();
    if (t < 64) {
      float a = swS[0][t] + swS[1][t] + swS[2][t] + swS[3][t];
      float b = swQ[0][t] + swQ[1][t] + swQ[2][t] + swQ[3][t];
      atomicAdd(&g.Cf[(bm + t) * 2], a);
      atomicAdd(&g.Cf[(bm + t) * 2 + 1], b);
    }
  }
}

// ---------------------------------------------------------------------------
// MFMA flash attention: direct-fragment K/V loads (no LDS staging), wave-
// private key quarters, barrier-free loop. LDS only for the P transpose and
// final 4-way merge. Base-2 softmax (Q pre-scaled by log2e/sqrt(DH)).
// Grid: (128 q-tiles of 16, 8 = desc*4+head). Block 256 = 4 waves.
// ---------------------------------------------------------------------------
__global__ __launch_bounds__(256, 4) void attn_mfma_kernel(
    const unsigned short* __restrict__ Qb0, const unsigned short* __restrict__ Kt0,
    const unsigned short* __restrict__ Vb0, const unsigned short* __restrict__ Qb1,
    const unsigned short* __restrict__ Kt1, const unsigned short* __restrict__ Vb1,
    unsigned short* __restrict__ mgT0, unsigned short* __restrict__ mgT1, int cross) {
  const int z = blockIdx.y, desc = z >> 2, h = z & 3;
  const int t = threadIdx.x;
  const int wid = t >> 6, lane = t & 63;
  const int col = lane & 15, Qd = lane >> 4;
  const int qb = blockIdx.x * 16;

  const unsigned short* Qb = desc ? Qb1 : Qb0;
  const int s = cross ? (1 - desc) : desc;
  const unsigned short* Kt = s ? Kt1 : Kt0;
  const unsigned short* Vb = s ? Vb1 : Vb0;

  // LDS: PW per-wave P scratch (4 x 640 shorts), then merge scratch
  // fS = 2432 floats at short-offset 2560. Total 7424 shorts = 14.5 KB.
  __shared__ __align__(16) unsigned short SM[7424];
  unsigned short* PW = SM + wid * 640;
  float* fS = (float*)(SM + 2560);

  bf16x8 bq;
  {
    union { unsigned short u[8]; bf16x8 v; } tmp;
#pragma unroll
    for (int j = 0; j < 8; ++j)
      tmp.u[j] = Qb[(size_t)(h * 32 + Qd * 8 + j) * NN + qb + col];
    bq = tmp.v;
  }

  f32x4 o0 = {0.f, 0.f, 0.f, 0.f}, o1 = {0.f, 0.f, 0.f, 0.f};
  float m = -1e30f, l = 0.f;

  const int kq = wid * 512;
#pragma unroll 2
  for (int it = 0; it < 16; ++it) {
    const int k0 = kq + it * 32;
    bf16x8 aK0 = *(const bf16x8*)&Kt[((size_t)h * NN + k0 + col) * 32 + Qd * 8];
    bf16x8 aK1 = *(const bf16x8*)&Kt[((size_t)h * NN + k0 + 16 + col) * 32 + Qd * 8];
    bf16x8 av0 = *(const bf16x8*)&Vb[(size_t)(h * 32 + col) * NN + k0 + Qd * 8];
    bf16x8 av1 = *(const bf16x8*)&Vb[(size_t)(h * 32 + 16 + col) * NN + k0 + Qd * 8];
    f32x4 z4 = {0.f, 0.f, 0.f, 0.f};
    f32x4 s0 = __builtin_amdgcn_mfma_f32_16x16x32_bf16(aK0, bq, z4, 0, 0, 0);
    f32x4 s1 = __builtin_amdgcn_mfma_f32_16x16x32_bf16(aK1, bq, z4, 0, 0, 0);
    float cm = fmaxf(fmaxf(fmaxf(s0[0], s0[1]), fmaxf(s0[2], s0[3])),
                     fmaxf(fmaxf(s1[0], s1[1]), fmaxf(s1[2], s1[3])));
    cm = fmaxf(cm, __shfl_xor(cm, 16));
    cm = fmaxf(cm, __shfl_xor(cm, 32));
    const float mn = fmaxf(m, cm);
    const float alpha = exp2f(m - mn);
    m = mn;
    float p00 = exp2f(s0[0] - mn), p01 = exp2f(s0[1] - mn);
    float p02 = exp2f(s0[2] - mn), p03 = exp2f(s0[3] - mn);
    float p10 = exp2f(s1[0] - mn), p11 = exp2f(s1[1] - mn);
    float p12 = exp2f(s1[2] - mn), p13 = exp2f(s1[3] - mn);
    float us = (p00 + p01) + (p02 + p03) + (p10 + p11) + (p12 + p13);
    us += __shfl_xor(us, 16);
    us += __shfl_xor(us, 32);
    l = l * alpha + us;
    uint2 w0 = { pk2(p00, p01), pk2(p02, p03) };
    uint2 w1 = { pk2(p10, p11), pk2(p12, p13) };
    *(uint2*)&PW[col * 40 + Qd * 4] = w0;
    *(uint2*)&PW[col * 40 + 16 + Qd * 4] = w1;
    bf16x8 pb = *(const bf16x8*)&PW[col * 40 + Qd * 8];
    o0 = o0 * alpha;
    o1 = o1 * alpha;
    o0 = __builtin_amdgcn_mfma_f32_16x16x32_bf16(av0, pb, o0, 0, 0, 0);
    o1 = __builtin_amdgcn_mfma_f32_16x16x32_bf16(av1, pb, o1, 0, 0, 0);
  }

  // ---- 4-way merge across key quarters via LDS ----
  __syncthreads();
  *(float4*)&fS[wid * 576 + col * 36 + Qd * 4] =
      make_float4(o0[0], o0[1], o0[2], o0[3]);
  *(float4*)&fS[wid * 576 + col * 36 + 16 + Qd * 4] =
      make_float4(o1[0], o1[1], o1[2], o1[3]);
  if (Qd == 0) {
    fS[2304 + wid * 16 + col] = m;
    fS[2368 + wid * 16 + col] = l;
  }
  __syncthreads();
  {
    const int q16 = t >> 4, dg = t & 15;
    float m0 = fS[2304 + q16], m1 = fS[2304 + 16 + q16];
    float m2 = fS[2304 + 32 + q16], m3 = fS[2304 + 48 + q16];
    float M = fmaxf(fmaxf(m0, m1), fmaxf(m2, m3));
    float w0 = exp2f(m0 - M), w1 = exp2f(m1 - M);
    float w2 = exp2f(m2 - M), w3 = exp2f(m3 - M);
    float L = w0 * fS[2368 + q16] + w1 * fS[2368 + 16 + q16] +
              w2 * fS[2368 + 32 + q16] + w3 * fS[2368 + 48 + q16];
    float inv = 1.0f / L;
    unsigned short* T = desc ? mgT1 : mgT0;
    const int q = qb + q16;
#pragma unroll
    for (int r = 0; r < 2; ++r) {
      int d = dg * 2 + r;
      float v = (w0 * fS[0 * 576 + q16 * 36 + d] + w1 * fS[1 * 576 + q16 * 36 + d] +
                 w2 * fS[2 * 576 + q16 * 36 + d] + w3 * fS[3 * 576 + q16 * 36 + d]) * inv;
      T[(size_t)q * 128 + d * 4 + h] = (unsigned short)f2bf(v);
    }
  }
}

// ---------------------------------------------------------------------------
extern "C" void kernel_launch(void* const* d_in, const int* in_sizes, int n_in,
                              void* d_out, int out_size, void* d_ws, size_t ws_size,
                              hipStream_t stream) {
  const float* desc0 = (const float*)d_in[0];
  const float* desc1 = (const float*)d_in[1];
  const float* Wq = (const float*)d_in[2];
  const float* bq = (const float*)d_in[3];
  const float* Wk = (const float*)d_in[4];
  const float* bk = (const float*)d_in[5];
  const float* Wv = (const float*)d_in[6];
  const float* bv = (const float*)d_in[7];
  const float* Wm = (const float*)d_in[8];
  const float* bmv = (const float*)d_in[9];
  const float* W1 = (const float*)d_in[10];
  const float* b1 = (const float*)d_in[11];
  const float* W2 = (const float*)d_in[12];
  const float* b2 = (const float*)d_in[13];

  float* out0 = (float*)d_out;
  float* out1 = out0 + (size_t)DDIM * NN;

  float* fws = (float*)d_ws;
  float* Sg0 = fws;                    // 512
  float* Sg1 = Sg0 + 512;              // 512
  float* b1m = Sg1 + 512;              // 1536
  unsigned short* uws = (unsigned short*)(b1m + 1536);
  unsigned short* dT0 = uws;                     // 262144 each
  unsigned short* dT1 = uws + 1 * 262144;
  unsigned short* Qb0 = uws + 2 * 262144;
  unsigned short* Qb1 = uws + 3 * 262144;
  unsigned short* Kt0 = uws + 4 * 262144;
  unsigned short* Kt1 = uws + 5 * 262144;
  unsigned short* Vb0 = uws + 6 * 262144;
  unsigned short* Vb1 = uws + 7 * 262144;
  unsigned short* mgT0 = uws + 8 * 262144;
  unsigned short* mgT1 = uws + 9 * 262144;
  unsigned short* HT0 = uws + 10 * 262144;       // 524288
  unsigned short* HT1 = HT0 + 524288;            // 524288
  unsigned short* Wqkv = HT1 + 524288;           // 294912
  unsigned short* Wb2 = Wqkv + 294912;           // 196608
  unsigned short* Wmix = Wb2 + 196608;           // 393216

  setup_kernel<<<784, 256, 0, stream>>>(Wq, Wk, Wv, Wm, W1, W2, bmv, b1,
                                        desc0, desc1, Wqkv, Wb2, Wmix, b1m,
                                        dT0, dT1, out0, out1);

  for (int l = 0; l < NL; ++l) {
    const int cross = l & 1;
    const unsigned short* wq = Wqkv + l * 16384;
    const unsigned short* wk = Wqkv + 98304 + l * 16384;
    const unsigned short* wv = Wqkv + 196608 + l * 16384;
    const unsigned short* wmx = Wmix + l * 65536;
    const unsigned short* w2 = Wb2 + l * 32768;
    const float* bqp = bq + (size_t)l * 128;
    const float* bkp = bk + (size_t)l * 128;
    const float* bvp = bv + (size_t)l * 128;
    const float* b1p = b1m + (size_t)l * 256;
    const float* b2p = b2 + (size_t)l * 128;

    MOps8 Pq = {};
    Pq.op[0] = {wq, bqp, dT0, nullptr, Qb0, Sg0, nullptr, 128, 0, 0};
    Pq.op[1] = {wq, bqp, dT1, nullptr, Qb1, Sg1, nullptr, 128, 0, 0};
    Pq.op[2] = {wk, bkp, dT0, nullptr, Kt0, nullptr, nullptr, 128, 0, 1};
    Pq.op[3] = {wk, bkp, dT1, nullptr, Kt1, nullptr, nullptr, 128, 0, 1};
    Pq.op[4] = {wv, bvp, dT0, nullptr, Vb0, nullptr, nullptr, 128, 0, 2};
    Pq.op[5] = {wv, bvp, dT1, nullptr, Vb1, nullptr, nullptr, 128, 0, 2};
    gemm_direct_kernel<128><<<dim3(32, 2, 6), 256, 0, stream>>>(Pq);

    attn_mfma_kernel<<<dim3(128, 8), 256, 0, stream>>>(
        Qb0, Kt0, Vb0, Qb1, Kt1, Vb1, mgT0, mgT1, cross);

    MOps8 P1 = {};
    P1.op[0] = {wmx, b1p, dT0, mgT0, HT0, Sg0, nullptr, 128, 256, 5};
    P1.op[1] = {wmx, b1p, dT1, mgT1, HT1, Sg1, nullptr, 128, 256, 5};
    gemm_direct_kernel<256><<<dim3(32, 4, 2), 256, 0, stream>>>(P1);

    MOps8 P2 = {};
    P2.op[0] = {w2, b2p, HT0, nullptr, dT0, out0, Sg0, 256, 128, 4};
    P2.op[1] = {w2, b2p, HT1, nullptr, dT1, out1, Sg1, 256, 128, 4};
    gemm_direct_kernel<256><<<dim3(32, 2, 2), 256, 0, stream>>>(P2);
  }
}